// Round 2
// baseline (50736.124 us; speedup 1.0000x reference)
//
#include <hip/hip_runtime.h>
#include <hip/hip_bf16.h>
#include <math.h>

#define BB 64
#define TT 1024
#define EE 256
#define HH 512

// ws layout (floats)
#define H0_OFF   0          // [2][64][512]
#define H1_OFF   65536      // [2][64][512]
#define RH0_OFF  131072     // [64][512]
#define RH1_OFF  163840     // [64][512]
#define CTR_FLT  196608     // counters live after this (as ints)
#define WS_BYTES (786432 + 8*256)

__device__ __forceinline__ float gload(const float* p) {
    return __hip_atomic_load(p, __ATOMIC_RELAXED, __HIP_MEMORY_SCOPE_AGENT);
}
__device__ __forceinline__ void gstore(float* p, float v) {
    __hip_atomic_store(p, v, __ATOMIC_RELAXED, __HIP_MEMORY_SCOPE_AGENT);
}
__device__ __forceinline__ float sigm(float x) { return 1.f / (1.f + expf(-x)); }

// Partial dot for 2 gates over one k-segment. Thread handles column c with
// weight rows w1p/w2p; k-chunk is interleaved: k = koff + 32*i. All 8 batch
// rows accumulate from LDS (S, row stride SROW). Weight float4 loaded ONCE
// per 8 batch rows -> 8x less L2 traffic than R1.
template<int NIT, int SROW>
__device__ __forceinline__ void dot2seg(const float* __restrict__ w1p,
                                        const float* __restrict__ w2p,
                                        const float* __restrict__ S,
                                        int koff, float aR[8], float aZ[8]) {
    #pragma unroll 4
    for (int i = 0; i < NIT; ++i) {
        const int k = koff + 32 * i;
        float4 w1 = *(const float4*)(w1p + k);
        float4 w2 = *(const float4*)(w2p + k);
        #pragma unroll
        for (int b = 0; b < 8; ++b) {
            float4 xv = *(const float4*)(S + b * SROW + k);
            aR[b] = fmaf(w1.x, xv.x, fmaf(w1.y, xv.y, fmaf(w1.z, xv.z, fmaf(w1.w, xv.w, aR[b]))));
            aZ[b] = fmaf(w2.x, xv.x, fmaf(w2.y, xv.y, fmaf(w2.z, xv.z, fmaf(w2.w, xv.w, aZ[b]))));
        }
    }
}
template<int NIT, int SROW>
__device__ __forceinline__ void dot1seg(const float* __restrict__ w1p,
                                        const float* __restrict__ S,
                                        int koff, float aH[8]) {
    #pragma unroll 4
    for (int i = 0; i < NIT; ++i) {
        const int k = koff + 32 * i;
        float4 w1 = *(const float4*)(w1p + k);
        #pragma unroll
        for (int b = 0; b < 8; ++b) {
            float4 xv = *(const float4*)(S + b * SROW + k);
            aH[b] = fmaf(w1.x, xv.x, fmaf(w1.y, xv.y, fmaf(w1.z, xv.z, fmaf(w1.w, xv.w, aH[b]))));
        }
    }
}

__device__ __forceinline__ void butterfly8(float v[8]) {
    #pragma unroll
    for (int m = 4; m >= 1; m >>= 1) {
        #pragma unroll
        for (int b = 0; b < 8; ++b) v[b] += __shfl_xor(v[b], m, 64);
    }
}
__device__ __forceinline__ float pick8(const float v[8], int p) {
    float r = v[0];
    #pragma unroll
    for (int b = 1; b < 8; ++b) if (p == b) r = v[b];
    return r;
}

__device__ __forceinline__ void domain_barrier(int* ctr, int target) {
    __syncthreads();
    if (threadIdx.x == 0) {
        __hip_atomic_fetch_add(ctr, 1, __ATOMIC_RELEASE, __HIP_MEMORY_SCOPE_AGENT);
        while (__hip_atomic_load(ctr, __ATOMIC_RELAXED, __HIP_MEMORY_SCOPE_AGENT) < target)
            __builtin_amdgcn_s_sleep(1);
    }
    __syncthreads();
}

__global__ __launch_bounds__(256, 1) void gru_main(
    const int* __restrict__ tokens, const float* __restrict__ emb,
    const float* __restrict__ Wr0, const float* __restrict__ br0,
    const float* __restrict__ Wz0, const float* __restrict__ bz0,
    const float* __restrict__ Wh0, const float* __restrict__ bh0,
    const float* __restrict__ Wr1, const float* __restrict__ br1,
    const float* __restrict__ Wz1, const float* __restrict__ bz1,
    const float* __restrict__ Wh1, const float* __restrict__ bh1,
    float* __restrict__ ws)
{
    const int blk = blockIdx.x;
    const int g = blk >> 5;       // batch group 0..7
    const int j = blk & 31;       // column slice; j%8 = XCD -> weight L2 affinity
    const int tid = threadIdx.x;
    const int layer = tid >> 7;   // 0 or 1
    const int lt = tid & 127;
    const int w = lt >> 6;        // wave within layer
    const int lane = lt & 63;
    const int cg = lane >> 3;     // col within wave (broadcast group)
    const int p8 = lane & 7;      // k-slice; also this lane's batch row after reduce
    const int cl = w * 8 + cg;    // 0..15
    const int c = j * 16 + cl;    // global hidden column
    const int koff = 4 * p8;
    const int bg = g * 8 + p8;    // global batch row owned after reduction

    float* h0buf = ws + H0_OFF;
    float* h1buf = ws + H1_OFF;
    float* rh0 = ws + RH0_OFF;
    float* rh1 = ws + RH1_OFF;
    int* ctr = (int*)(ws + CTR_FLT) + g * 64;

    const int K = layer ? 1024 : 768;
    const int len1 = layer ? 512 : 256;
    const float* wrRow = (layer ? Wr1 : Wr0) + (size_t)c * K;
    const float* wzRow = (layer ? Wz1 : Wz0) + (size_t)c * K;
    const float* whRow = (layer ? Wh1 : Wh0) + (size_t)c * K;
    const float bR = (layer ? br1 : br0)[c];
    const float bZ = (layer ? bz1 : bz0)[c];
    const float bH = (layer ? bh1 : bh0)[c];

    // flat LDS; staging writes are lane-consecutive (2-way alias = free),
    // compute reads are 8 unique b128 covering all 32 banks (conflict-free)
    __shared__ float sx[2048];    // x_t  [8][256]
    __shared__ float sh0[4096];   // h0 prev/out [8][512]
    __shared__ float sh1[4096];   // h1 prev [8][512]
    __shared__ float sr0[4096];   // r*h layer0 [8][512]
    __shared__ float sr1[4096];   // r*h layer1 [8][512]

    int target = 32;
    for (int s = 0; s <= 1024; ++s) {
        const int rd0 = (s & 1) ^ 1;   // h0 read slot
        // ---- P1 staging: flat copies, coalesced, conflict-free ----
        {
            const float* src0 = h0buf + rd0 * 32768 + g * 4096;
            const float* src1 = h1buf + (s & 1) * 32768 + g * 4096;
            #pragma unroll
            for (int q = 0; q < 16; ++q) sh0[tid + 256 * q] = gload(src0 + tid + 256 * q);
            #pragma unroll
            for (int q = 0; q < 16; ++q) sh1[tid + 256 * q] = gload(src1 + tid + 256 * q);
            if (s < 1024) {
                #pragma unroll
                for (int q = 0; q < 8; ++q) {
                    int tok = tokens[(g * 8 + q) * 1024 + s];
                    sx[tid + 256 * q] = emb[(size_t)tok * 256 + tid];
                }
            }
        }
        __syncthreads();

        const bool act = layer ? (s >= 1) : (s < 1024);
        float zv = 0.f, hp = 0.f;
        if (act) {
            float aR[8] = {0,0,0,0,0,0,0,0}, aZ[8] = {0,0,0,0,0,0,0,0};
            if (layer == 0) {
                dot2seg<8, 256>(wrRow, wzRow, sx, koff, aR, aZ);
                dot2seg<16, 512>(wrRow + 256, wzRow + 256, sh0, koff, aR, aZ);
            } else {
                dot2seg<16, 512>(wrRow, wzRow, sh0, koff, aR, aZ);
                dot2seg<16, 512>(wrRow + 512, wzRow + 512, sh1, koff, aR, aZ);
            }
            butterfly8(aR);
            butterfly8(aZ);
            float rv = sigm(pick8(aR, p8) + bR);
            zv = sigm(pick8(aZ, p8) + bZ);
            hp = layer ? sh1[p8 * 512 + c] : sh0[p8 * 512 + c];
            float* rhb = layer ? rh1 : rh0;
            gstore(rhb + bg * 512 + c, rv * hp);
        }
        domain_barrier(ctr, target); target += 32;

        // ---- P2 staging ----
        {
            const float* src0 = rh0 + g * 4096;
            const float* src1 = rh1 + g * 4096;
            #pragma unroll
            for (int q = 0; q < 16; ++q) sr0[tid + 256 * q] = gload(src0 + tid + 256 * q);
            #pragma unroll
            for (int q = 0; q < 16; ++q) sr1[tid + 256 * q] = gload(src1 + tid + 256 * q);
        }
        __syncthreads();

        if (act) {
            float aH[8] = {0,0,0,0,0,0,0,0};
            if (layer == 0) {
                dot1seg<8, 256>(whRow, sx, koff, aH);
                dot1seg<16, 512>(whRow + 256, sr0, koff, aH);
            } else {
                dot1seg<16, 512>(whRow, sh0, koff, aH);
                dot1seg<16, 512>(whRow + 512, sr1, koff, aH);
            }
            butterfly8(aH);
            float ht = tanhf(pick8(aH, p8) + bH);
            float hn = (1.f - zv) * hp + zv * ht;
            float* hb = layer ? (h1buf + ((s - 1) & 1) * 32768)
                              : (h0buf + (s & 1) * 32768);
            gstore(hb + bg * 512 + c, hn);
        }
        domain_barrier(ctr, target); target += 32;
    }
}

__global__ __launch_bounds__(128) void gru_fc(
    const float* __restrict__ h1f, const float* __restrict__ fcW,
    const float* __restrict__ fcb, float* __restrict__ out)
{
    int tid = threadIdx.x;
    int b = tid >> 1, cc = tid & 1;
    const float* hrow = h1f + b * 512;
    const float* wrow = fcW + cc * 512;
    float acc = 0.f;
    #pragma unroll 4
    for (int k = 0; k < 512; k += 4) {
        float4 hv = *(const float4*)(hrow + k);
        float4 wv = *(const float4*)(wrow + k);
        acc = fmaf(hv.x, wv.x, fmaf(hv.y, wv.y, fmaf(hv.z, wv.z, fmaf(hv.w, wv.w, acc))));
    }
    out[b * 2 + cc] = acc + fcb[cc];
}

extern "C" void kernel_launch(void* const* d_in, const int* in_sizes, int n_in,
                              void* d_out, int out_size, void* d_ws, size_t ws_size,
                              hipStream_t stream) {
    const int* tokens = (const int*)d_in[0];
    const float* emb = (const float*)d_in[1];
    const float* Wr0 = (const float*)d_in[2];  const float* br0 = (const float*)d_in[3];
    const float* Wz0 = (const float*)d_in[4];  const float* bz0 = (const float*)d_in[5];
    const float* Wh0 = (const float*)d_in[6];  const float* bh0 = (const float*)d_in[7];
    const float* Wr1 = (const float*)d_in[8];  const float* br1 = (const float*)d_in[9];
    const float* Wz1 = (const float*)d_in[10]; const float* bz1 = (const float*)d_in[11];
    const float* Wh1 = (const float*)d_in[12]; const float* bh1 = (const float*)d_in[13];
    const float* fcW = (const float*)d_in[14]; const float* fcb = (const float*)d_in[15];
    float* ws = (float*)d_ws;

    hipMemsetAsync(d_ws, 0, WS_BYTES, stream);

    gru_main<<<256, 256, 0, stream>>>(tokens, emb, Wr0, br0, Wz0, bz0, Wh0, bh0,
                                      Wr1, br1, Wz1, bz1, Wh1, bh1, ws);
    // final hidden state of layer 1: t=1023 -> slot 1
    gru_fc<<<1, 128, 0, stream>>>(ws + H1_OFF + 32768, fcW, fcb, (float*)d_out);
}